// Round 13
// baseline (197.355 us; speedup 1.0000x reference)
//
#include <hip/hip_runtime.h>

#define B_ 4
#define S_ 2048
#define H_ 1024
#define NH_ 16
#define HD_ 64
// SCALE * log2(e): QK^T lands in log2 domain; exp -> v_exp_f32 (2^x) directly
#define QSCALE_ 0.1803368801111204f

typedef __attribute__((ext_vector_type(8))) short bf16x8;
typedef __attribute__((ext_vector_type(4))) float f32x4;
typedef __attribute__((ext_vector_type(16))) float f32x16;

__device__ __forceinline__ unsigned short f2bf(float f) {
    unsigned u = __float_as_uint(f);
    unsigned r = (u + 0x7FFFu + ((u >> 16) & 1u)) >> 16;
    return (unsigned short)r;
}
__device__ __forceinline__ float exp2f_hw(float x) { return __builtin_amdgcn_exp2f(x); }

// ---------------- fused cast fp32 -> bf16 for x + 4 weights (1 launch) ----------------
__global__ __launch_bounds__(256) void cast_all(const float* __restrict__ x,
                                                const float* __restrict__ Wq,
                                                const float* __restrict__ Wk,
                                                const float* __restrict__ Wv,
                                                const float* __restrict__ Wo,
                                                unsigned short* __restrict__ xb,
                                                unsigned short* __restrict__ Wqb,
                                                unsigned short* __restrict__ Wkb,
                                                unsigned short* __restrict__ Wvb,
                                                unsigned short* __restrict__ Wob) {
    int bid = blockIdx.x;
    const float* src;
    unsigned short* dst;
    int i;
    if (bid < 8192) {  // x: 8.4M elems / 4 / 256
        src = x; dst = xb; i = bid * 256 + threadIdx.x;
    } else {
        int k = bid - 8192, wsel = k >> 10;
        src = wsel == 0 ? Wq : wsel == 1 ? Wk : wsel == 2 ? Wv : Wo;
        dst = wsel == 0 ? Wqb : wsel == 1 ? Wkb : wsel == 2 ? Wvb : Wob;
        i = (k & 1023) * 256 + threadIdx.x;
    }
    float4 v = reinterpret_cast<const float4*>(src)[i];
    ushort4 o;
    o.x = f2bf(v.x); o.y = f2bf(v.y); o.z = f2bf(v.z); o.w = f2bf(v.w);
    reinterpret_cast<ushort4*>(dst)[i] = o;
}

// ---------------- staging: rows x 128 bytes, XOR slot-swizzled ----------------
// 256-thread (4-wave) version: each wave stages 4KB (32 rows)
__device__ __forceinline__ void stage128_swz(const char* g, int gstride, char* lds, int tid) {
    int wave = tid >> 6, lane = tid & 63;
#pragma unroll
    for (int j = 0; j < 4; ++j) {
        int o = ((wave * 4 + j) * 64 + lane) * 16;
        int r = o >> 7;
        int slot = (o >> 4) & 7;
        const char* src = g + (size_t)r * gstride + ((slot ^ (r & 7)) << 4);
        __builtin_amdgcn_global_load_lds((const __attribute__((address_space(1))) void*)src,
                                         (__attribute__((address_space(3))) void*)(lds + (wave * 4 + j) * 1024),
                                         16, 0, 0);
    }
}
// 512-thread (8-wave) version: each wave stages 1KB (8 rows of a 64x128B tile)
__device__ __forceinline__ void stage64_swz8(const char* g, int gstride, char* lds, int tid) {
    int wave = tid >> 6, lane = tid & 63;
    int o = (wave * 64 + lane) * 16;
    int r = o >> 7;                 // wave*8 + lane>>3
    int slot = (o >> 4) & 7;        // lane&7
    const char* src = g + (size_t)r * gstride + ((slot ^ (r & 7)) << 4);
    __builtin_amdgcn_global_load_lds((const __attribute__((address_space(1))) void*)src,
                                     (__attribute__((address_space(3))) void*)(lds + wave * 1024 + lane * 16),
                                     16, 0, 0);
}

__device__ __forceinline__ bf16x8 frag_swz(const char* lds, int row, int slot) {
    return *reinterpret_cast<const bf16x8*>(lds + row * 128 + (((slot) ^ (row & 7)) << 4));
}

__device__ __forceinline__ float vmax16(const f32x16& v) {
    float a0 = fmaxf(v[0], v[1]), a1 = fmaxf(v[2], v[3]);
    float a2 = fmaxf(v[4], v[5]), a3 = fmaxf(v[6], v[7]);
    float a4 = fmaxf(v[8], v[9]), a5 = fmaxf(v[10], v[11]);
    float a6 = fmaxf(v[12], v[13]), a7 = fmaxf(v[14], v[15]);
    float b0 = fmaxf(a0, a1), b1 = fmaxf(a2, a3), b2 = fmaxf(a4, a5), b3 = fmaxf(a6, a7);
    return fmaxf(fmaxf(b0, b1), fmaxf(b2, b3));
}

// ---------------- fused QKV projection GEMM: C[M,N] = A[M,K] * W[N,K]^T ----------------
// 2D grid (64,24), single-buffer 2-barrier loop. Swapped MFMA (mfma(W,x)) -> thread holds
// 4 consecutive out-cols of one row -> vectorized 8B bf16 epilogue stores.
__global__ __launch_bounds__(256) void gemm_qkv(const unsigned short* __restrict__ xb,
                                                const unsigned short* __restrict__ Wq,
                                                const unsigned short* __restrict__ Wk,
                                                const unsigned short* __restrict__ Wv,
                                                unsigned short* __restrict__ Qo,
                                                unsigned short* __restrict__ Ko,
                                                unsigned short* __restrict__ Vo) {
    __shared__ __align__(16) char As[16384];
    __shared__ __align__(16) char Bs[16384];
    int tid = threadIdx.x, lane = tid & 63, wave = tid >> 6;
    int wr = wave >> 1, wc = wave & 1;
    int brow = blockIdx.x * 128;
    int mat = blockIdx.y >> 3;
    int bcol = (blockIdx.y & 7) * 128;
    const unsigned short* W = mat == 0 ? Wq : (mat == 1 ? Wk : Wv);
    unsigned short* O = mat == 0 ? Qo : (mat == 1 ? Ko : Vo);
    float oscale = (mat == 0) ? QSCALE_ : 1.0f;  // fold attn scale + log2e into Q
    f32x4 acc[4][4] = {};
    const char* ga = (const char*)(xb + (size_t)brow * H_);
    const char* gb = (const char*)(W + (size_t)bcol * H_);
    int ro = lane & 15, kg = lane >> 4;
    for (int kt = 0; kt < 16; ++kt) {
        stage128_swz(ga + kt * 128, H_ * 2, As, tid);
        stage128_swz(gb + kt * 128, H_ * 2, Bs, tid);
        __syncthreads();
#pragma unroll
        for (int kk = 0; kk < 2; ++kk) {
            bf16x8 af[4], bfr[4];
#pragma unroll
            for (int m = 0; m < 4; ++m) af[m] = frag_swz(As, wr * 64 + m * 16 + ro, kk * 4 + kg);
#pragma unroll
            for (int n = 0; n < 4; ++n) bfr[n] = frag_swz(Bs, wc * 64 + n * 16 + ro, kk * 4 + kg);
#pragma unroll
            for (int m = 0; m < 4; ++m)
#pragma unroll
                for (int n = 0; n < 4; ++n)   // swapped: A-op = W (out col), B-op = x (out row)
                    acc[m][n] = __builtin_amdgcn_mfma_f32_16x16x32_bf16(bfr[n], af[m], acc[m][n], 0, 0, 0);
        }
        __syncthreads();
    }
    // epilogue: thread holds out-row (ro) x 4 consecutive out-cols (kg*4+i) per (m,n)
#pragma unroll
    for (int m = 0; m < 4; ++m) {
        int grow = brow + wr * 64 + m * 16 + ro;
#pragma unroll
        for (int n = 0; n < 4; ++n) {
            int gcol = bcol + wc * 64 + n * 16 + kg * 4;
            float p0 = acc[m][n][0] * oscale, p1 = acc[m][n][1] * oscale;
            float p2 = acc[m][n][2] * oscale, p3 = acc[m][n][3] * oscale;
            unsigned w0, w1;
            asm("v_cvt_pk_bf16_f32 %0, %1, %2" : "=v"(w0) : "v"(p0), "v"(p1));
            asm("v_cvt_pk_bf16_f32 %0, %1, %2" : "=v"(w1) : "v"(p2), "v"(p3));
            uint2 pk; pk.x = w0; pk.y = w1;
            *reinterpret_cast<uint2*>(O + (size_t)grow * H_ + gcol) = pk;
        }
    }
}

// ---------------- output projection GEMM + bias, fp32 out ----------------
// R9-exact version (reverted from swapped epilogue: R10-12 totals suggest it cost ~7us).
__global__ __launch_bounds__(256) void gemm_out(const unsigned short* __restrict__ Ab,
                                                const unsigned short* __restrict__ Wo,
                                                const float* __restrict__ bo,
                                                float* __restrict__ out) {
    __shared__ __align__(16) char As[16384];
    __shared__ __align__(16) char Bs[16384];
    int tid = threadIdx.x, lane = tid & 63, wave = tid >> 6;
    int wr = wave >> 1, wc = wave & 1;
    int brow = blockIdx.x * 128;
    int bcol = blockIdx.y * 128;
    f32x4 acc[4][4] = {};
    const char* ga = (const char*)(Ab + (size_t)brow * H_);
    const char* gb = (const char*)(Wo + (size_t)bcol * H_);
    int ro = lane & 15, kg = lane >> 4;
    for (int kt = 0; kt < 16; ++kt) {
        stage128_swz(ga + kt * 128, H_ * 2, As, tid);
        stage128_swz(gb + kt * 128, H_ * 2, Bs, tid);
        __syncthreads();
#pragma unroll
        for (int kk = 0; kk < 2; ++kk) {
            bf16x8 af[4], bfr[4];
#pragma unroll
            for (int m = 0; m < 4; ++m) af[m] = frag_swz(As, wr * 64 + m * 16 + ro, kk * 4 + kg);
#pragma unroll
            for (int n = 0; n < 4; ++n) bfr[n] = frag_swz(Bs, wc * 64 + n * 16 + ro, kk * 4 + kg);
#pragma unroll
            for (int m = 0; m < 4; ++m)
#pragma unroll
                for (int n = 0; n < 4; ++n)
                    acc[m][n] = __builtin_amdgcn_mfma_f32_16x16x32_bf16(af[m], bfr[n], acc[m][n], 0, 0, 0);
        }
        __syncthreads();
    }
#pragma unroll
    for (int n = 0; n < 4; ++n) {
        int col = bcol + wc * 64 + n * 16 + ro;
        float bn = bo[col];
#pragma unroll
        for (int m = 0; m < 4; ++m)
#pragma unroll
            for (int i = 0; i < 4; ++i) {
                int row = brow + wr * 64 + m * 16 + kg * 4 + i;
                out[(size_t)row * H_ + col] = acc[m][n][i] + bn;
            }
    }
}

// ---------------- flash attention: 8 waves x 32 q-rows (QBLK=256), KV tile = 128 ----------------
// R7-verified two-barrier skeleton, R9-measured balanced decode. KV processed 128/tile as
// two sequential 64-halves (byte-identical per-half body) -> barrier/vmcnt drains halve.
__global__ __launch_bounds__(512) void attn(const unsigned short* __restrict__ Q,
                                            const unsigned short* __restrict__ K,
                                            const unsigned short* __restrict__ V,
                                            const int* __restrict__ amask,
                                            unsigned short* __restrict__ Ab) {
    __shared__ __align__(16) char lds[51264];
    char* Ksm = lds;                                              // 32KB K dbuf (2 x 16KB, halves at +0/+8KB)
    unsigned short* Vt2 = (unsigned short*)(lds + 32768);         // 16KB V^T, two 8KB halves
    unsigned char* maskc = (unsigned char*)(lds + 49152);         // 2KB
    unsigned char* anyz = (unsigned char*)(lds + 51200);          // 32B
    // epilogue reuses first 32KB as O-transpose buffer

    int tid = threadIdx.x, lane = tid & 63, w = tid >> 6;        // w 0..7
    int l31 = lane & 31, hi = lane >> 5, hi4 = hi * 4;
    int id = blockIdx.x;
    int g = id >> 6;
    int qb = (g < 4) ? (7 - 2 * g) : (2 * g - 8);   // balanced pairs: qb(g)+qb(g+4)=7, heavy first
    int bh = id & 63, b = bh >> 4, h = bh & 15;
    int brow = qb * 256;
    int Qwg = brow + w * 32;          // wave's q-base; lane's q-row = Qwg + l31

    // per-lane causal bitmask for the diagonal 32x32 sub-block (kv_local > q_local)
    unsigned cm = 0;
#pragma unroll
    for (int r = 0; r < 16; ++r)
        if (((r & 3) + 8 * (r >> 2) + hi4) > l31) cm |= (1u << r);

    const unsigned short* Qg = Q + (size_t)(b * S_ + Qwg + l31) * H_ + h * HD_;
    const unsigned short* Kg = K + (size_t)b * S_ * H_ + h * HD_;
    const unsigned short* Vg = V + (size_t)b * S_ * H_ + h * HD_;

    // prologue: stage K(0) (both halves); load V(0); hoist padding mask; load Q frags
    stage64_swz8((const char*)Kg, H_ * 2, Ksm, tid);
    stage64_swz8((const char*)(Kg + (size_t)64 * H_), H_ * 2, Ksm + 8192, tid);
    int vr = tid & 63, vd0 = (tid >> 6) * 8;    // thread owns (kv=vr / vr+64, d=vd0..vd0+7)
    bf16x8 vreg[2];
    vreg[0] = *reinterpret_cast<const bf16x8*>(Vg + (size_t)vr * H_ + vd0);
    vreg[1] = *reinterpret_cast<const bf16x8*>(Vg + (size_t)(vr + 64) * H_ + vd0);
    {
        const int4* am4 = reinterpret_cast<const int4*>(amask + b * S_);
        int i = tid;
        if (i < S_ / 4) {
            int4 v = am4[i];
            uchar4 o;
            o.x = (v.x == 0); o.y = (v.y == 0); o.z = (v.z == 0); o.w = (v.w == 0);
            reinterpret_cast<uchar4*>(maskc)[i] = o;
        }
    }
    bf16x8 qf[4];
#pragma unroll
    for (int kk = 0; kk < 4; ++kk)
        qf[kk] = *reinterpret_cast<const bf16x8*>(Qg + kk * 16 + hi * 8);

    __syncthreads();  // prologue: K(0)/V(0) drained; maskc visible
    if (tid < 32) {   // per-64-kv "any masked" byte (covered by barrier #1 of t=0)
        const unsigned* mw = reinterpret_cast<const unsigned*>(maskc + tid * 64);
        unsigned o = 0;
#pragma unroll
        for (int i = 0; i < 16; ++i) o |= mw[i];
        anyz[tid] = o ? 1 : 0;
    }

    f32x16 oacc0, oacc1;
#pragma unroll
    for (int j = 0; j < 16; ++j) { oacc0[j] = 0.f; oacc1[j] = 0.f; }
    float mrun = -__builtin_inff(), lrun = 0.f;

    int T = 2 * qb + 2;                   // 128-kv tiles
    for (int t = 0; t < T; ++t) {
        int kv0 = t * 128;

        // scatter vreg (= V(t), both halves) -> Vt2, cheap factored swizzle addressing
#pragma unroll
        for (int h2 = 0; h2 < 2; ++h2) {
            unsigned short* vb = Vt2 + h2 * 4096 + vd0 * 64 + (vr & 7);
            int rs3 = (vr >> 3) << 3;
#pragma unroll
            for (int j = 0; j < 8; ++j)
                vb[j * 64 + (rs3 ^ (j << 3))] = (unsigned short)vreg[h2][j];
        }
        __syncthreads();  // #1: Vt2 visible; K(t) already drained (prev #2 / prologue)

        // stage K(t+1) (both halves) into other buffer; prefetch V(t+1) into registers
        if (t + 1 < T) {
            char* kdst = Ksm + ((t + 1) & 1) * 16384;
            stage64_swz8((const char*)(Kg + (size_t)(kv0 + 128) * H_), H_ * 2, kdst, tid);
            stage64_swz8((const char*)(Kg + (size_t)(kv0 + 192) * H_), H_ * 2, kdst + 8192, tid);
        }
        {
            int kvn = (t + 1 < T) ? kv0 + 128 : kv0;
            vreg[0] = *reinterpret_cast<const bf16x8*>(Vg + (size_t)(kvn + vr) * H_ + vd0);
            vreg[1] = *reinterpret_cast<const bf16x8*>(Vg + (size_t)(kvn + 64 + vr) * H_ + vd0);
        }

#pragma unroll
        for (int half = 0; half < 2; ++half) {
            int kvh = kv0 + half * 64;
            const char* Kc = Ksm + (t & 1) * 16384 + half * 8192;
            const unsigned short* Vtc = Vt2 + half * 4096;

            int c0 = kvh, c1 = kvh + 32;
            if (c0 <= Qwg) {             // wave-uniform: any visible work in this half
                bool vis1 = (c1 <= Qwg);
                f32x16 sa0, sa1;
#pragma unroll
                for (int j = 0; j < 16; ++j) { sa0[j] = 0.f; sa1[j] = 0.f; }

                __builtin_amdgcn_s_setprio(1);
#pragma unroll
                for (int kk = 0; kk < 4; ++kk) {
                    bf16x8 kf0 = frag_swz(Kc, l31, 2 * kk + hi);
                    sa0 = __builtin_amdgcn_mfma_f32_32x32x16_bf16(kf0, qf[kk], sa0, 0, 0, 0);
                    if (vis1) {
                        bf16x8 kf1 = frag_swz(Kc, 32 + l31, 2 * kk + hi);
                        sa1 = __builtin_amdgcn_mfma_f32_32x32x16_bf16(kf1, qf[kk], sa1, 0, 0, 0);
                    }
                }
                __builtin_amdgcn_s_setprio(0);

                // causal: diagonal sub-block at most once per wave
                if (c0 == Qwg) {
#pragma unroll
                    for (int r = 0; r < 16; ++r) sa0[r] = (cm & (1u << r)) ? -1e9f : sa0[r];
                }
                if (vis1 && c1 == Qwg) {
#pragma unroll
                    for (int r = 0; r < 16; ++r) sa1[r] = (cm & (1u << r)) ? -1e9f : sa1[r];
                }
                // padding mask (skipped when this 64-kv group is all-ones)
                if (anyz[2 * t + half]) {
#pragma unroll
                    for (int u = 0; u < 4; ++u) {
                        uchar4 mk = *reinterpret_cast<const uchar4*>(maskc + kvh + 8 * u + hi4);
                        if (mk.x) sa0[4 * u + 0] = -1e9f;
                        if (mk.y) sa0[4 * u + 1] = -1e9f;
                        if (mk.z) sa0[4 * u + 2] = -1e9f;
                        if (mk.w) sa0[4 * u + 3] = -1e9f;
                    }
                    if (vis1) {
#pragma unroll
                        for (int u = 0; u < 4; ++u) {
                            uchar4 mk = *reinterpret_cast<const uchar4*>(maskc + kvh + 32 + 8 * u + hi4);
                            if (mk.x) sa1[4 * u + 0] = -1e9f;
                            if (mk.y) sa1[4 * u + 1] = -1e9f;
                            if (mk.z) sa1[4 * u + 2] = -1e9f;
                            if (mk.w) sa1[4 * u + 3] = -1e9f;
                        }
                    }
                }

                // tree row-max; cross-half via shfl
                float mx = vmax16(sa0);
                if (vis1) mx = fmaxf(mx, vmax16(sa1));
                mx = fmaxf(mx, __shfl_xor(mx, 32));

                // threshold defer-rescale: only pay the O-pass when max grows by >10 (log2)
                if (__any(mx > mrun + 10.f)) {
                    float mnew = fmaxf(mrun, mx);
                    float fsc = exp2f_hw(mrun - mnew);
                    mrun = mnew;
                    lrun *= fsc;
#pragma unroll
                    for (int j = 0; j < 16; ++j) { oacc0[j] *= fsc; oacc1[j] *= fsc; }
                }

                // fused per-n: exp2 -> pack bf16 -> permlane -> PV MFMA
                float rs = 0.f;
                __builtin_amdgcn_s_setprio(1);
#pragma unroll
                for (int n = 0; n < 2; ++n) {
                    if (n == 1 && !vis1) break;
                    const f32x16& sa = (n == 0) ? sa0 : sa1;
                    unsigned int wrd[4][2];
#pragma unroll
                    for (int u = 0; u < 4; ++u) {
                        float p0 = exp2f_hw(sa[4 * u + 0] - mrun);
                        float p1 = exp2f_hw(sa[4 * u + 1] - mrun);
                        float p2 = exp2f_hw(sa[4 * u + 2] - mrun);
                        float p3 = exp2f_hw(sa[4 * u + 3] - mrun);
                        rs += (p0 + p1) + (p2 + p3);
                        asm("v_cvt_pk_bf16_f32 %0, %1, %2" : "=v"(wrd[u][0]) : "v"(p0), "v"(p1));
                        asm("v_cvt_pk_bf16_f32 %0, %1, %2" : "=v"(wrd[u][1]) : "v"(p2), "v"(p3));
                    }
#pragma unroll
                    for (int hf = 0; hf < 2; ++hf) {
                        int u0 = 2 * hf;
                        unsigned int X0 = wrd[u0][0], Y0 = wrd[u0 + 1][0];
                        unsigned int X1 = wrd[u0][1], Y1 = wrd[u0 + 1][1];
                        asm("v_permlane32_swap_b32 %0, %1" : "+v"(X0), "+v"(Y0));
                        asm("v_permlane32_swap_b32 %0, %1" : "+v"(X1), "+v"(Y1));
                        union { unsigned int u[4]; bf16x8 v; } bu;
                        bu.u[0] = X0; bu.u[1] = X1; bu.u[2] = Y0; bu.u[3] = Y1;
                        int kc = 2 * n + hf;
                        bf16x8 af0 = *reinterpret_cast<const bf16x8*>(
                            &Vtc[(l31) * 64 + (((2 * kc + hi) ^ (l31 & 7)) << 3)]);
                        oacc0 = __builtin_amdgcn_mfma_f32_32x32x16_bf16(af0, bu.v, oacc0, 0, 0, 0);
                        bf16x8 af1 = *reinterpret_cast<const bf16x8*>(
                            &Vtc[(32 + l31) * 64 + (((2 * kc + hi) ^ (l31 & 7)) << 3)]);
                        oacc1 = __builtin_amdgcn_mfma_f32_32x32x16_bf16(af1, bu.v, oacc1, 0, 0, 0);
                    }
                }
                __builtin_amdgcn_s_setprio(0);

                rs += __shfl_xor(rs, 32);
                lrun += rs;
            }
        }
        __syncthreads();  // #2: Vt2 reads done; K(t+1)/V(t+1) prefetch drained
    }

    // epilogue: divide by row sum, transpose O^T -> O via LDS (reuse first 32KB), store
    float inv = 1.f / lrun;
    unsigned short* Osm = reinterpret_cast<unsigned short*>(lds);
#pragma unroll
    for (int r = 0; r < 16; ++r) {
        int d = (r & 3) + 8 * (r >> 2) + hi4;
        Osm[w * 2048 + l31 * 64 + ((((d >> 3) ^ (l31 & 7)) << 3) | (d & 7))] = f2bf(oacc0[r] * inv);
        int d1 = d + 32;
        Osm[w * 2048 + l31 * 64 + ((((d1 >> 3) ^ (l31 & 7)) << 3) | (d1 & 7))] = f2bf(oacc1[r] * inv);
    }
    __syncthreads();
#pragma unroll
    for (int wv = 0; wv < 4; ++wv) {
        int q = tid >> 3, j = tid & 7;      // q 0..63
        int row = wv * 64 + q;              // 0..255
        bf16x8 vv = *reinterpret_cast<const bf16x8*>(
            Osm + (row >> 5) * 2048 + (row & 31) * 64 + ((j ^ (row & 7)) << 3));
        size_t grow = (size_t)(b * S_ + brow + row);
        *reinterpret_cast<bf16x8*>(Ab + grow * H_ + h * HD_ + j * 8) = vv;
    }
}

extern "C" void kernel_launch(void* const* d_in, const int* in_sizes, int n_in,
                              void* d_out, int out_size, void* d_ws, size_t ws_size,
                              hipStream_t stream) {
    const float* x  = (const float*)d_in[0];
    const int* amask = (const int*)d_in[1];
    const float* Wq = (const float*)d_in[2];
    const float* Wk = (const float*)d_in[3];
    const float* Wv = (const float*)d_in[4];
    const float* Wo = (const float*)d_in[5];
    const float* bo = (const float*)d_in[6];
    float* out = (float*)d_out;

    const size_t XN = (size_t)B_ * S_ * H_;   // 8388608
    const size_t WN = (size_t)H_ * H_;        // 1048576

    char* ws = (char*)d_ws;
    unsigned short* xb  = (unsigned short*)ws;           ws += XN * 2;
    unsigned short* Wqb = (unsigned short*)ws;           ws += WN * 2;
    unsigned short* Wkb = (unsigned short*)ws;           ws += WN * 2;
    unsigned short* Wvb = (unsigned short*)ws;           ws += WN * 2;
    unsigned short* Wob = (unsigned short*)ws;           ws += WN * 2;
    unsigned short* Qb  = (unsigned short*)ws;           ws += XN * 2;
    unsigned short* Kb  = (unsigned short*)ws;           ws += XN * 2;
    unsigned short* Vb  = (unsigned short*)ws;           ws += XN * 2;
    unsigned short* Ab  = (unsigned short*)ws;           ws += XN * 2;

    cast_all<<<12288, 256, 0, stream>>>(x, Wq, Wk, Wv, Wo, xb, Wqb, Wkb, Wvb, Wob);
    gemm_qkv<<<dim3(64, 24), 256, 0, stream>>>(xb, Wqb, Wkb, Wvb, Qb, Kb, Vb);
    attn<<<512, 512, 0, stream>>>(Qb, Kb, Vb, amask, Ab);
    gemm_out<<<dim3(64, 8), 256, 0, stream>>>(Ab, Wob, bo, out);
}

// Round 14
// 171.076 us; speedup vs baseline: 1.1536x; 1.1536x over previous
//
#include <hip/hip_runtime.h>

#define B_ 4
#define S_ 2048
#define H_ 1024
#define NH_ 16
#define HD_ 64
// SCALE * log2(e): QK^T lands in log2 domain; exp -> v_exp_f32 (2^x) directly
#define QSCALE_ 0.1803368801111204f

typedef __attribute__((ext_vector_type(8))) short bf16x8;
typedef __attribute__((ext_vector_type(4))) float f32x4;
typedef __attribute__((ext_vector_type(16))) float f32x16;

__device__ __forceinline__ unsigned short f2bf(float f) {
    unsigned u = __float_as_uint(f);
    unsigned r = (u + 0x7FFFu + ((u >> 16) & 1u)) >> 16;
    return (unsigned short)r;
}
__device__ __forceinline__ float exp2f_hw(float x) { return __builtin_amdgcn_exp2f(x); }

// ---------------- fused cast fp32 -> bf16 for x + 4 weights (1 launch) ----------------
__global__ __launch_bounds__(256) void cast_all(const float* __restrict__ x,
                                                const float* __restrict__ Wq,
                                                const float* __restrict__ Wk,
                                                const float* __restrict__ Wv,
                                                const float* __restrict__ Wo,
                                                unsigned short* __restrict__ xb,
                                                unsigned short* __restrict__ Wqb,
                                                unsigned short* __restrict__ Wkb,
                                                unsigned short* __restrict__ Wvb,
                                                unsigned short* __restrict__ Wob) {
    int bid = blockIdx.x;
    const float* src;
    unsigned short* dst;
    int i;
    if (bid < 8192) {  // x: 8.4M elems / 4 / 256
        src = x; dst = xb; i = bid * 256 + threadIdx.x;
    } else {
        int k = bid - 8192, wsel = k >> 10;
        src = wsel == 0 ? Wq : wsel == 1 ? Wk : wsel == 2 ? Wv : Wo;
        dst = wsel == 0 ? Wqb : wsel == 1 ? Wkb : wsel == 2 ? Wvb : Wob;
        i = (k & 1023) * 256 + threadIdx.x;
    }
    float4 v = reinterpret_cast<const float4*>(src)[i];
    ushort4 o;
    o.x = f2bf(v.x); o.y = f2bf(v.y); o.z = f2bf(v.z); o.w = f2bf(v.w);
    reinterpret_cast<ushort4*>(dst)[i] = o;
}

// ---------------- staging: rows x 128 bytes, XOR slot-swizzled ----------------
// 256-thread (4-wave) version: each wave stages 4KB (32 rows)
__device__ __forceinline__ void stage128_swz(const char* g, int gstride, char* lds, int tid) {
    int wave = tid >> 6, lane = tid & 63;
#pragma unroll
    for (int j = 0; j < 4; ++j) {
        int o = ((wave * 4 + j) * 64 + lane) * 16;
        int r = o >> 7;
        int slot = (o >> 4) & 7;
        const char* src = g + (size_t)r * gstride + ((slot ^ (r & 7)) << 4);
        __builtin_amdgcn_global_load_lds((const __attribute__((address_space(1))) void*)src,
                                         (__attribute__((address_space(3))) void*)(lds + (wave * 4 + j) * 1024),
                                         16, 0, 0);
    }
}
// 512-thread (8-wave) version: each wave stages 1KB (8 rows of a 64x128B tile)
__device__ __forceinline__ void stage64_swz8(const char* g, int gstride, char* lds, int tid) {
    int wave = tid >> 6, lane = tid & 63;
    int o = (wave * 64 + lane) * 16;
    int r = o >> 7;                 // wave*8 + lane>>3
    int slot = (o >> 4) & 7;        // lane&7
    const char* src = g + (size_t)r * gstride + ((slot ^ (r & 7)) << 4);
    __builtin_amdgcn_global_load_lds((const __attribute__((address_space(1))) void*)src,
                                     (__attribute__((address_space(3))) void*)(lds + wave * 1024 + lane * 16),
                                     16, 0, 0);
}

__device__ __forceinline__ bf16x8 frag_swz(const char* lds, int row, int slot) {
    return *reinterpret_cast<const bf16x8*>(lds + row * 128 + (((slot) ^ (row & 7)) << 4));
}

__device__ __forceinline__ float vmax16(const f32x16& v) {
    float a0 = fmaxf(v[0], v[1]), a1 = fmaxf(v[2], v[3]);
    float a2 = fmaxf(v[4], v[5]), a3 = fmaxf(v[6], v[7]);
    float a4 = fmaxf(v[8], v[9]), a5 = fmaxf(v[10], v[11]);
    float a6 = fmaxf(v[12], v[13]), a7 = fmaxf(v[14], v[15]);
    float b0 = fmaxf(a0, a1), b1 = fmaxf(a2, a3), b2 = fmaxf(a4, a5), b3 = fmaxf(a6, a7);
    return fmaxf(fmaxf(b0, b1), fmaxf(b2, b3));
}

// ---------------- fused QKV projection GEMM: C[M,N] = A[M,K] * W[N,K]^T ----------------
// 2D grid (64,24), single-buffer 2-barrier loop. Swapped MFMA (mfma(W,x)) -> thread holds
// 4 consecutive out-cols of one row -> vectorized 8B bf16 epilogue stores. (R12-measured.)
__global__ __launch_bounds__(256) void gemm_qkv(const unsigned short* __restrict__ xb,
                                                const unsigned short* __restrict__ Wq,
                                                const unsigned short* __restrict__ Wk,
                                                const unsigned short* __restrict__ Wv,
                                                unsigned short* __restrict__ Qo,
                                                unsigned short* __restrict__ Ko,
                                                unsigned short* __restrict__ Vo) {
    __shared__ __align__(16) char As[16384];
    __shared__ __align__(16) char Bs[16384];
    int tid = threadIdx.x, lane = tid & 63, wave = tid >> 6;
    int wr = wave >> 1, wc = wave & 1;
    int brow = blockIdx.x * 128;
    int mat = blockIdx.y >> 3;
    int bcol = (blockIdx.y & 7) * 128;
    const unsigned short* W = mat == 0 ? Wq : (mat == 1 ? Wk : Wv);
    unsigned short* O = mat == 0 ? Qo : (mat == 1 ? Ko : Vo);
    float oscale = (mat == 0) ? QSCALE_ : 1.0f;  // fold attn scale + log2e into Q
    f32x4 acc[4][4] = {};
    const char* ga = (const char*)(xb + (size_t)brow * H_);
    const char* gb = (const char*)(W + (size_t)bcol * H_);
    int ro = lane & 15, kg = lane >> 4;
    for (int kt = 0; kt < 16; ++kt) {
        stage128_swz(ga + kt * 128, H_ * 2, As, tid);
        stage128_swz(gb + kt * 128, H_ * 2, Bs, tid);
        __syncthreads();
#pragma unroll
        for (int kk = 0; kk < 2; ++kk) {
            bf16x8 af[4], bfr[4];
#pragma unroll
            for (int m = 0; m < 4; ++m) af[m] = frag_swz(As, wr * 64 + m * 16 + ro, kk * 4 + kg);
#pragma unroll
            for (int n = 0; n < 4; ++n) bfr[n] = frag_swz(Bs, wc * 64 + n * 16 + ro, kk * 4 + kg);
#pragma unroll
            for (int m = 0; m < 4; ++m)
#pragma unroll
                for (int n = 0; n < 4; ++n)   // swapped: A-op = W (out col), B-op = x (out row)
                    acc[m][n] = __builtin_amdgcn_mfma_f32_16x16x32_bf16(bfr[n], af[m], acc[m][n], 0, 0, 0);
        }
        __syncthreads();
    }
    // epilogue: thread holds out-row (ro) x 4 consecutive out-cols (kg*4+i) per (m,n)
#pragma unroll
    for (int m = 0; m < 4; ++m) {
        int grow = brow + wr * 64 + m * 16 + ro;
#pragma unroll
        for (int n = 0; n < 4; ++n) {
            int gcol = bcol + wc * 64 + n * 16 + kg * 4;
            float p0 = acc[m][n][0] * oscale, p1 = acc[m][n][1] * oscale;
            float p2 = acc[m][n][2] * oscale, p3 = acc[m][n][3] * oscale;
            unsigned w0, w1;
            asm("v_cvt_pk_bf16_f32 %0, %1, %2" : "=v"(w0) : "v"(p0), "v"(p1));
            asm("v_cvt_pk_bf16_f32 %0, %1, %2" : "=v"(w1) : "v"(p2), "v"(p3));
            uint2 pk; pk.x = w0; pk.y = w1;
            *reinterpret_cast<uint2*>(O + (size_t)grow * H_ + gcol) = pk;
        }
    }
}

// ---------------- output projection GEMM + bias, fp32 out (R9-exact) ----------------
__global__ __launch_bounds__(256) void gemm_out(const unsigned short* __restrict__ Ab,
                                                const unsigned short* __restrict__ Wo,
                                                const float* __restrict__ bo,
                                                float* __restrict__ out) {
    __shared__ __align__(16) char As[16384];
    __shared__ __align__(16) char Bs[16384];
    int tid = threadIdx.x, lane = tid & 63, wave = tid >> 6;
    int wr = wave >> 1, wc = wave & 1;
    int brow = blockIdx.x * 128;
    int bcol = blockIdx.y * 128;
    f32x4 acc[4][4] = {};
    const char* ga = (const char*)(Ab + (size_t)brow * H_);
    const char* gb = (const char*)(Wo + (size_t)bcol * H_);
    int ro = lane & 15, kg = lane >> 4;
    for (int kt = 0; kt < 16; ++kt) {
        stage128_swz(ga + kt * 128, H_ * 2, As, tid);
        stage128_swz(gb + kt * 128, H_ * 2, Bs, tid);
        __syncthreads();
#pragma unroll
        for (int kk = 0; kk < 2; ++kk) {
            bf16x8 af[4], bfr[4];
#pragma unroll
            for (int m = 0; m < 4; ++m) af[m] = frag_swz(As, wr * 64 + m * 16 + ro, kk * 4 + kg);
#pragma unroll
            for (int n = 0; n < 4; ++n) bfr[n] = frag_swz(Bs, wc * 64 + n * 16 + ro, kk * 4 + kg);
#pragma unroll
            for (int m = 0; m < 4; ++m)
#pragma unroll
                for (int n = 0; n < 4; ++n)
                    acc[m][n] = __builtin_amdgcn_mfma_f32_16x16x32_bf16(af[m], bfr[n], acc[m][n], 0, 0, 0);
        }
        __syncthreads();
    }
#pragma unroll
    for (int n = 0; n < 4; ++n) {
        int col = bcol + wc * 64 + n * 16 + ro;
        float bn = bo[col];
#pragma unroll
        for (int m = 0; m < 4; ++m)
#pragma unroll
            for (int i = 0; i < 4; ++i) {
                int row = brow + wr * 64 + m * 16 + kg * 4 + i;
                out[(size_t)row * H_ + col] = acc[m][n][i] + bn;
            }
    }
}

// ---------------- flash attention: 8 waves x 32 q-rows (QBLK=256), KVBLK=64 ----------------
// R9-EXACT: two-barrier skeleton, balanced decode. (R13's 128-kv-tile variant regressed
// 58->105us: doubled body -> VGPR collapse to 72 + occupancy loss. Loop-body edits are
// new templates; this is the verified one.)
__global__ __launch_bounds__(512) void attn(const unsigned short* __restrict__ Q,
                                            const unsigned short* __restrict__ K,
                                            const unsigned short* __restrict__ V,
                                            const int* __restrict__ amask,
                                            unsigned short* __restrict__ Ab) {
    __shared__ __align__(16) char lds[32768];
    char* Ksm = lds;                                             // 16KB K dbuf
    unsigned short* Vt = (unsigned short*)(lds + 16384);         // 8KB V^T swizzled
    unsigned char* maskc = (unsigned char*)(lds + 24576);        // 2KB
    unsigned char* anyz = (unsigned char*)(lds + 26624);         // 32B
    // epilogue reuses all 32KB as O-transpose buffer

    int tid = threadIdx.x, lane = tid & 63, w = tid >> 6;        // w 0..7
    int l31 = lane & 31, hi = lane >> 5, hi4 = hi * 4;
    int id = blockIdx.x;
    int g = id >> 6;
    int qb = (g < 4) ? (7 - 2 * g) : (2 * g - 8);   // balanced pairs: qb(g)+qb(g+4)=7, heavy first
    int bh = id & 63, b = bh >> 4, h = bh & 15;
    int brow = qb * 256;
    int Qwg = brow + w * 32;          // wave's q-base; lane's q-row = Qwg + l31

    // per-lane causal bitmask for the diagonal 32x32 sub-block (kv_local > q_local)
    unsigned cm = 0;
#pragma unroll
    for (int r = 0; r < 16; ++r)
        if (((r & 3) + 8 * (r >> 2) + hi4) > l31) cm |= (1u << r);

    const unsigned short* Qg = Q + (size_t)(b * S_ + Qwg + l31) * H_ + h * HD_;
    const unsigned short* Kg = K + (size_t)b * S_ * H_ + h * HD_;
    const unsigned short* Vg = V + (size_t)b * S_ * H_ + h * HD_;

    // prologue: stage K(0); load V(0); hoist padding mask; load Q frags
    stage64_swz8((const char*)Kg, H_ * 2, Ksm, tid);
    int vr = tid & 63, vd0 = (tid >> 6) * 8;    // each thread owns (kv=vr, d=vd0..vd0+7)
    bf16x8 vreg = *reinterpret_cast<const bf16x8*>(Vg + (size_t)vr * H_ + vd0);
    {
        const int4* am4 = reinterpret_cast<const int4*>(amask + b * S_);
        int i = tid;
        if (i < S_ / 4) {
            int4 v = am4[i];
            uchar4 o;
            o.x = (v.x == 0); o.y = (v.y == 0); o.z = (v.z == 0); o.w = (v.w == 0);
            reinterpret_cast<uchar4*>(maskc)[i] = o;
        }
    }
    bf16x8 qf[4];
#pragma unroll
    for (int kk = 0; kk < 4; ++kk)
        qf[kk] = *reinterpret_cast<const bf16x8*>(Qg + kk * 16 + hi * 8);

    __syncthreads();  // prologue: K(0)/V(0) drained; maskc visible
    if (tid < 32) {   // per-64-kv "any masked" byte (covered by barrier #1 of t=0)
        const unsigned* mw = reinterpret_cast<const unsigned*>(maskc + tid * 64);
        unsigned o = 0;
#pragma unroll
        for (int i = 0; i < 16; ++i) o |= mw[i];
        anyz[tid] = o ? 1 : 0;
    }

    f32x16 oacc0, oacc1;
#pragma unroll
    for (int j = 0; j < 16; ++j) { oacc0[j] = 0.f; oacc1[j] = 0.f; }
    float mrun = -__builtin_inff(), lrun = 0.f;

    int T = 4 * qb + 4;
    for (int t = 0; t < T; ++t) {
        int kv0 = t * 64;
        const char* Kc = Ksm + (t & 1) * 8192;

        // scatter vreg (= V(t)) -> Vt, cheap factored swizzle addressing
        {
            unsigned short* vb = Vt + vd0 * 64 + (vr & 7);
            int rs3 = (vr >> 3) << 3;
#pragma unroll
            for (int j = 0; j < 8; ++j)
                vb[j * 64 + (rs3 ^ (j << 3))] = (unsigned short)vreg[j];
        }
        __syncthreads();  // #1: Vt visible; K(t) already drained (prev #2 / prologue)

        // stage K(t+1) into other buffer; prefetch V(t+1) into registers
        if (t + 1 < T)
            stage64_swz8((const char*)(Kg + (size_t)(kv0 + 64) * H_), H_ * 2,
                         Ksm + ((t + 1) & 1) * 8192, tid);
        {
            int kvn = (t + 1 < T) ? kv0 + 64 : kv0;
            vreg = *reinterpret_cast<const bf16x8*>(Vg + (size_t)(kvn + vr) * H_ + vd0);
        }

        int c0 = kv0, c1 = kv0 + 32;
        if (c0 <= Qwg) {             // wave-uniform: any visible work in this tile
            bool vis1 = (c1 <= Qwg);
            f32x16 sa0, sa1;
#pragma unroll
            for (int j = 0; j < 16; ++j) { sa0[j] = 0.f; sa1[j] = 0.f; }

            __builtin_amdgcn_s_setprio(1);
#pragma unroll
            for (int kk = 0; kk < 4; ++kk) {
                bf16x8 kf0 = frag_swz(Kc, l31, 2 * kk + hi);
                sa0 = __builtin_amdgcn_mfma_f32_32x32x16_bf16(kf0, qf[kk], sa0, 0, 0, 0);
                if (vis1) {
                    bf16x8 kf1 = frag_swz(Kc, 32 + l31, 2 * kk + hi);
                    sa1 = __builtin_amdgcn_mfma_f32_32x32x16_bf16(kf1, qf[kk], sa1, 0, 0, 0);
                }
            }
            __builtin_amdgcn_s_setprio(0);

            // causal: diagonal sub-block at most once per wave
            if (c0 == Qwg) {
#pragma unroll
                for (int r = 0; r < 16; ++r) sa0[r] = (cm & (1u << r)) ? -1e9f : sa0[r];
            }
            if (vis1 && c1 == Qwg) {
#pragma unroll
                for (int r = 0; r < 16; ++r) sa1[r] = (cm & (1u << r)) ? -1e9f : sa1[r];
            }
            // padding mask (skipped when this 64-kv group is all-ones)
            if (anyz[t]) {
#pragma unroll
                for (int u = 0; u < 4; ++u) {
                    uchar4 mk = *reinterpret_cast<const uchar4*>(maskc + kv0 + 8 * u + hi4);
                    if (mk.x) sa0[4 * u + 0] = -1e9f;
                    if (mk.y) sa0[4 * u + 1] = -1e9f;
                    if (mk.z) sa0[4 * u + 2] = -1e9f;
                    if (mk.w) sa0[4 * u + 3] = -1e9f;
                }
                if (vis1) {
#pragma unroll
                    for (int u = 0; u < 4; ++u) {
                        uchar4 mk = *reinterpret_cast<const uchar4*>(maskc + kv0 + 32 + 8 * u + hi4);
                        if (mk.x) sa1[4 * u + 0] = -1e9f;
                        if (mk.y) sa1[4 * u + 1] = -1e9f;
                        if (mk.z) sa1[4 * u + 2] = -1e9f;
                        if (mk.w) sa1[4 * u + 3] = -1e9f;
                    }
                }
            }

            // tree row-max; cross-half via shfl
            float mx = vmax16(sa0);
            if (vis1) mx = fmaxf(mx, vmax16(sa1));
            mx = fmaxf(mx, __shfl_xor(mx, 32));

            // threshold defer-rescale: only pay the O-pass when max grows by >10 (log2)
            if (__any(mx > mrun + 10.f)) {
                float mnew = fmaxf(mrun, mx);
                float fsc = exp2f_hw(mrun - mnew);
                mrun = mnew;
                lrun *= fsc;
#pragma unroll
                for (int j = 0; j < 16; ++j) { oacc0[j] *= fsc; oacc1[j] *= fsc; }
            }

            // fused per-n: exp2 -> pack bf16 -> permlane -> PV MFMA
            float rs = 0.f;
            __builtin_amdgcn_s_setprio(1);
#pragma unroll
            for (int n = 0; n < 2; ++n) {
                if (n == 1 && !vis1) break;
                const f32x16& sa = (n == 0) ? sa0 : sa1;
                unsigned int wrd[4][2];
#pragma unroll
                for (int u = 0; u < 4; ++u) {
                    float p0 = exp2f_hw(sa[4 * u + 0] - mrun);
                    float p1 = exp2f_hw(sa[4 * u + 1] - mrun);
                    float p2 = exp2f_hw(sa[4 * u + 2] - mrun);
                    float p3 = exp2f_hw(sa[4 * u + 3] - mrun);
                    rs += (p0 + p1) + (p2 + p3);
                    asm("v_cvt_pk_bf16_f32 %0, %1, %2" : "=v"(wrd[u][0]) : "v"(p0), "v"(p1));
                    asm("v_cvt_pk_bf16_f32 %0, %1, %2" : "=v"(wrd[u][1]) : "v"(p2), "v"(p3));
                }
#pragma unroll
                for (int half = 0; half < 2; ++half) {
                    int u0 = 2 * half;
                    unsigned int X0 = wrd[u0][0], Y0 = wrd[u0 + 1][0];
                    unsigned int X1 = wrd[u0][1], Y1 = wrd[u0 + 1][1];
                    asm("v_permlane32_swap_b32 %0, %1" : "+v"(X0), "+v"(Y0));
                    asm("v_permlane32_swap_b32 %0, %1" : "+v"(X1), "+v"(Y1));
                    union { unsigned int u[4]; bf16x8 v; } bu;
                    bu.u[0] = X0; bu.u[1] = X1; bu.u[2] = Y0; bu.u[3] = Y1;
                    int kc = 2 * n + half;
                    bf16x8 af0 = *reinterpret_cast<const bf16x8*>(
                        &Vt[(l31) * 64 + (((2 * kc + hi) ^ (l31 & 7)) << 3)]);
                    oacc0 = __builtin_amdgcn_mfma_f32_32x32x16_bf16(af0, bu.v, oacc0, 0, 0, 0);
                    bf16x8 af1 = *reinterpret_cast<const bf16x8*>(
                        &Vt[(32 + l31) * 64 + (((2 * kc + hi) ^ (l31 & 7)) << 3)]);
                    oacc1 = __builtin_amdgcn_mfma_f32_32x32x16_bf16(af1, bu.v, oacc1, 0, 0, 0);
                }
            }
            __builtin_amdgcn_s_setprio(0);

            rs += __shfl_xor(rs, 32);
            lrun += rs;
        }
        __syncthreads();  // #2: Vt reads done; K(t+1)/V(t+1) prefetch drained
    }

    // epilogue: divide by row sum, transpose O^T -> O via LDS (reuse all 32KB), store
    float inv = 1.f / lrun;
    unsigned short* Osm = reinterpret_cast<unsigned short*>(lds);
#pragma unroll
    for (int r = 0; r < 16; ++r) {
        int d = (r & 3) + 8 * (r >> 2) + hi4;
        Osm[w * 2048 + l31 * 64 + ((((d >> 3) ^ (l31 & 7)) << 3) | (d & 7))] = f2bf(oacc0[r] * inv);
        int d1 = d + 32;
        Osm[w * 2048 + l31 * 64 + ((((d1 >> 3) ^ (l31 & 7)) << 3) | (d1 & 7))] = f2bf(oacc1[r] * inv);
    }
    __syncthreads();
#pragma unroll
    for (int wv = 0; wv < 4; ++wv) {
        int q = tid >> 3, j = tid & 7;      // q 0..63
        int row = wv * 64 + q;              // 0..255
        bf16x8 vv = *reinterpret_cast<const bf16x8*>(
            Osm + (row >> 5) * 2048 + (row & 31) * 64 + ((j ^ (row & 7)) << 3));
        size_t grow = (size_t)(b * S_ + brow + row);
        *reinterpret_cast<bf16x8*>(Ab + grow * H_ + h * HD_ + j * 8) = vv;
    }
}

extern "C" void kernel_launch(void* const* d_in, const int* in_sizes, int n_in,
                              void* d_out, int out_size, void* d_ws, size_t ws_size,
                              hipStream_t stream) {
    const float* x  = (const float*)d_in[0];
    const int* amask = (const int*)d_in[1];
    const float* Wq = (const float*)d_in[2];
    const float* Wk = (const float*)d_in[3];
    const float* Wv = (const float*)d_in[4];
    const float* Wo = (const float*)d_in[5];
    const float* bo = (const float*)d_in[6];
    float* out = (float*)d_out;

    const size_t XN = (size_t)B_ * S_ * H_;   // 8388608
    const size_t WN = (size_t)H_ * H_;        // 1048576

    char* ws = (char*)d_ws;
    unsigned short* xb  = (unsigned short*)ws;           ws += XN * 2;
    unsigned short* Wqb = (unsigned short*)ws;           ws += WN * 2;
    unsigned short* Wkb = (unsigned short*)ws;           ws += WN * 2;
    unsigned short* Wvb = (unsigned short*)ws;           ws += WN * 2;
    unsigned short* Wob = (unsigned short*)ws;           ws += WN * 2;
    unsigned short* Qb  = (unsigned short*)ws;           ws += XN * 2;
    unsigned short* Kb  = (unsigned short*)ws;           ws += XN * 2;
    unsigned short* Vb  = (unsigned short*)ws;           ws += XN * 2;
    unsigned short* Ab  = (unsigned short*)ws;           ws += XN * 2;

    cast_all<<<12288, 256, 0, stream>>>(x, Wq, Wk, Wv, Wo, xb, Wqb, Wkb, Wvb, Wob);
    gemm_qkv<<<dim3(64, 24), 256, 0, stream>>>(xb, Wqb, Wkb, Wvb, Qb, Kb, Vb);
    attn<<<512, 512, 0, stream>>>(Qb, Kb, Vb, amask, Ab);
    gemm_out<<<dim3(64, 8), 256, 0, stream>>>(Ab, Wob, bo, out);
}

// Round 15
// 165.392 us; speedup vs baseline: 1.1933x; 1.0344x over previous
//
#include <hip/hip_runtime.h>

#define B_ 4
#define S_ 2048
#define H_ 1024
#define NH_ 16
#define HD_ 64
// SCALE * log2(e): QK^T lands in log2 domain; exp -> v_exp_f32 (2^x) directly
#define QSCALE_ 0.1803368801111204f

typedef __attribute__((ext_vector_type(8))) short bf16x8;
typedef __attribute__((ext_vector_type(4))) float f32x4;
typedef __attribute__((ext_vector_type(16))) float f32x16;

__device__ __forceinline__ unsigned short f2bf(float f) {
    unsigned u = __float_as_uint(f);
    unsigned r = (u + 0x7FFFu + ((u >> 16) & 1u)) >> 16;
    return (unsigned short)r;
}
__device__ __forceinline__ float exp2f_hw(float x) { return __builtin_amdgcn_exp2f(x); }

// ---------------- fused cast fp32 -> bf16 for x + 4 weights (1 launch) ----------------
__global__ __launch_bounds__(256) void cast_all(const float* __restrict__ x,
                                                const float* __restrict__ Wq,
                                                const float* __restrict__ Wk,
                                                const float* __restrict__ Wv,
                                                const float* __restrict__ Wo,
                                                unsigned short* __restrict__ xb,
                                                unsigned short* __restrict__ Wqb,
                                                unsigned short* __restrict__ Wkb,
                                                unsigned short* __restrict__ Wvb,
                                                unsigned short* __restrict__ Wob) {
    int bid = blockIdx.x;
    const float* src;
    unsigned short* dst;
    int i;
    if (bid < 8192) {  // x: 8.4M elems / 4 / 256
        src = x; dst = xb; i = bid * 256 + threadIdx.x;
    } else {
        int k = bid - 8192, wsel = k >> 10;
        src = wsel == 0 ? Wq : wsel == 1 ? Wk : wsel == 2 ? Wv : Wo;
        dst = wsel == 0 ? Wqb : wsel == 1 ? Wkb : wsel == 2 ? Wvb : Wob;
        i = (k & 1023) * 256 + threadIdx.x;
    }
    float4 v = reinterpret_cast<const float4*>(src)[i];
    ushort4 o;
    o.x = f2bf(v.x); o.y = f2bf(v.y); o.z = f2bf(v.z); o.w = f2bf(v.w);
    reinterpret_cast<ushort4*>(dst)[i] = o;
}

// ---------------- staging: rows x 128 bytes, XOR slot-swizzled ----------------
// 256-thread (4-wave) version: each wave stages 4KB (32 rows)
__device__ __forceinline__ void stage128_swz(const char* g, int gstride, char* lds, int tid) {
    int wave = tid >> 6, lane = tid & 63;
#pragma unroll
    for (int j = 0; j < 4; ++j) {
        int o = ((wave * 4 + j) * 64 + lane) * 16;
        int r = o >> 7;
        int slot = (o >> 4) & 7;
        const char* src = g + (size_t)r * gstride + ((slot ^ (r & 7)) << 4);
        __builtin_amdgcn_global_load_lds((const __attribute__((address_space(1))) void*)src,
                                         (__attribute__((address_space(3))) void*)(lds + (wave * 4 + j) * 1024),
                                         16, 0, 0);
    }
}
// 512-thread (8-wave) version: each wave stages 1KB (8 rows of a 64x128B tile)
__device__ __forceinline__ void stage64_swz8(const char* g, int gstride, char* lds, int tid) {
    int wave = tid >> 6, lane = tid & 63;
    int o = (wave * 64 + lane) * 16;
    int r = o >> 7;                 // wave*8 + lane>>3
    int slot = (o >> 4) & 7;        // lane&7
    const char* src = g + (size_t)r * gstride + ((slot ^ (r & 7)) << 4);
    __builtin_amdgcn_global_load_lds((const __attribute__((address_space(1))) void*)src,
                                     (__attribute__((address_space(3))) void*)(lds + wave * 1024 + lane * 16),
                                     16, 0, 0);
}

__device__ __forceinline__ bf16x8 frag_swz(const char* lds, int row, int slot) {
    return *reinterpret_cast<const bf16x8*>(lds + row * 128 + (((slot) ^ (row & 7)) << 4));
}

__device__ __forceinline__ float vmax16(const f32x16& v) {
    float a0 = fmaxf(v[0], v[1]), a1 = fmaxf(v[2], v[3]);
    float a2 = fmaxf(v[4], v[5]), a3 = fmaxf(v[6], v[7]);
    float a4 = fmaxf(v[8], v[9]), a5 = fmaxf(v[10], v[11]);
    float a6 = fmaxf(v[12], v[13]), a7 = fmaxf(v[14], v[15]);
    float b0 = fmaxf(a0, a1), b1 = fmaxf(a2, a3), b2 = fmaxf(a4, a5), b3 = fmaxf(a6, a7);
    return fmaxf(fmaxf(b0, b1), fmaxf(b2, b3));
}

// ---------------- fused QKV projection GEMM: C[M,N] = A[M,K] * W[N,K]^T ----------------
// R9-EXACT. 2D grid (64,24). Plain mfma(af,bfr) + scalar epilogue: totals with this
// version ran 164.8-166.8 vs 171-172.7 with the "improved" swapped epilogue (5 runs).
__global__ __launch_bounds__(256) void gemm_qkv(const unsigned short* __restrict__ xb,
                                                const unsigned short* __restrict__ Wq,
                                                const unsigned short* __restrict__ Wk,
                                                const unsigned short* __restrict__ Wv,
                                                unsigned short* __restrict__ Qo,
                                                unsigned short* __restrict__ Ko,
                                                unsigned short* __restrict__ Vo) {
    __shared__ __align__(16) char As[16384];
    __shared__ __align__(16) char Bs[16384];
    int tid = threadIdx.x, lane = tid & 63, wave = tid >> 6;
    int wr = wave >> 1, wc = wave & 1;
    int brow = blockIdx.x * 128;
    int mat = blockIdx.y >> 3;
    int bcol = (blockIdx.y & 7) * 128;
    const unsigned short* W = mat == 0 ? Wq : (mat == 1 ? Wk : Wv);
    unsigned short* O = mat == 0 ? Qo : (mat == 1 ? Ko : Vo);
    float oscale = (mat == 0) ? QSCALE_ : 1.0f;  // fold attn scale + log2e into Q
    f32x4 acc[4][4] = {};
    const char* ga = (const char*)(xb + (size_t)brow * H_);
    const char* gb = (const char*)(W + (size_t)bcol * H_);
    int ro = lane & 15, kg = lane >> 4;
    for (int kt = 0; kt < 16; ++kt) {
        stage128_swz(ga + kt * 128, H_ * 2, As, tid);
        stage128_swz(gb + kt * 128, H_ * 2, Bs, tid);
        __syncthreads();
#pragma unroll
        for (int kk = 0; kk < 2; ++kk) {
            bf16x8 af[4], bfr[4];
#pragma unroll
            for (int m = 0; m < 4; ++m) af[m] = frag_swz(As, wr * 64 + m * 16 + ro, kk * 4 + kg);
#pragma unroll
            for (int n = 0; n < 4; ++n) bfr[n] = frag_swz(Bs, wc * 64 + n * 16 + ro, kk * 4 + kg);
#pragma unroll
            for (int m = 0; m < 4; ++m)
#pragma unroll
                for (int n = 0; n < 4; ++n)
                    acc[m][n] = __builtin_amdgcn_mfma_f32_16x16x32_bf16(af[m], bfr[n], acc[m][n], 0, 0, 0);
        }
        __syncthreads();
    }
#pragma unroll
    for (int m = 0; m < 4; ++m)
#pragma unroll
        for (int n = 0; n < 4; ++n)
#pragma unroll
            for (int i = 0; i < 4; ++i) {
                int row = brow + wr * 64 + m * 16 + kg * 4 + i;
                int col = bcol + wc * 64 + n * 16 + ro;
                O[(size_t)row * H_ + col] = f2bf(acc[m][n][i] * oscale);
            }
}

// ---------------- output projection GEMM + bias, fp32 out (R9-exact) ----------------
__global__ __launch_bounds__(256) void gemm_out(const unsigned short* __restrict__ Ab,
                                                const unsigned short* __restrict__ Wo,
                                                const float* __restrict__ bo,
                                                float* __restrict__ out) {
    __shared__ __align__(16) char As[16384];
    __shared__ __align__(16) char Bs[16384];
    int tid = threadIdx.x, lane = tid & 63, wave = tid >> 6;
    int wr = wave >> 1, wc = wave & 1;
    int brow = blockIdx.x * 128;
    int bcol = blockIdx.y * 128;
    f32x4 acc[4][4] = {};
    const char* ga = (const char*)(Ab + (size_t)brow * H_);
    const char* gb = (const char*)(Wo + (size_t)bcol * H_);
    int ro = lane & 15, kg = lane >> 4;
    for (int kt = 0; kt < 16; ++kt) {
        stage128_swz(ga + kt * 128, H_ * 2, As, tid);
        stage128_swz(gb + kt * 128, H_ * 2, Bs, tid);
        __syncthreads();
#pragma unroll
        for (int kk = 0; kk < 2; ++kk) {
            bf16x8 af[4], bfr[4];
#pragma unroll
            for (int m = 0; m < 4; ++m) af[m] = frag_swz(As, wr * 64 + m * 16 + ro, kk * 4 + kg);
#pragma unroll
            for (int n = 0; n < 4; ++n) bfr[n] = frag_swz(Bs, wc * 64 + n * 16 + ro, kk * 4 + kg);
#pragma unroll
            for (int m = 0; m < 4; ++m)
#pragma unroll
                for (int n = 0; n < 4; ++n)
                    acc[m][n] = __builtin_amdgcn_mfma_f32_16x16x32_bf16(af[m], bfr[n], acc[m][n], 0, 0, 0);
        }
        __syncthreads();
    }
#pragma unroll
    for (int n = 0; n < 4; ++n) {
        int col = bcol + wc * 64 + n * 16 + ro;
        float bn = bo[col];
#pragma unroll
        for (int m = 0; m < 4; ++m)
#pragma unroll
            for (int i = 0; i < 4; ++i) {
                int row = brow + wr * 64 + m * 16 + kg * 4 + i;
                out[(size_t)row * H_ + col] = acc[m][n][i] + bn;
            }
    }
}

// ---------------- flash attention: 8 waves x 32 q-rows (QBLK=256), KVBLK=64 ----------------
// R9-EXACT: two-barrier skeleton, balanced decode (co-resident pairs sum to const work).
__global__ __launch_bounds__(512) void attn(const unsigned short* __restrict__ Q,
                                            const unsigned short* __restrict__ K,
                                            const unsigned short* __restrict__ V,
                                            const int* __restrict__ amask,
                                            unsigned short* __restrict__ Ab) {
    __shared__ __align__(16) char lds[32768];
    char* Ksm = lds;                                             // 16KB K dbuf
    unsigned short* Vt = (unsigned short*)(lds + 16384);         // 8KB V^T swizzled
    unsigned char* maskc = (unsigned char*)(lds + 24576);        // 2KB
    unsigned char* anyz = (unsigned char*)(lds + 26624);         // 32B
    // epilogue reuses all 32KB as O-transpose buffer

    int tid = threadIdx.x, lane = tid & 63, w = tid >> 6;        // w 0..7
    int l31 = lane & 31, hi = lane >> 5, hi4 = hi * 4;
    int id = blockIdx.x;
    int g = id >> 6;
    int qb = (g < 4) ? (7 - 2 * g) : (2 * g - 8);   // balanced pairs: qb(g)+qb(g+4)=7, heavy first
    int bh = id & 63, b = bh >> 4, h = bh & 15;
    int brow = qb * 256;
    int Qwg = brow + w * 32;          // wave's q-base; lane's q-row = Qwg + l31

    // per-lane causal bitmask for the diagonal 32x32 sub-block (kv_local > q_local)
    unsigned cm = 0;
#pragma unroll
    for (int r = 0; r < 16; ++r)
        if (((r & 3) + 8 * (r >> 2) + hi4) > l31) cm |= (1u << r);

    const unsigned short* Qg = Q + (size_t)(b * S_ + Qwg + l31) * H_ + h * HD_;
    const unsigned short* Kg = K + (size_t)b * S_ * H_ + h * HD_;
    const unsigned short* Vg = V + (size_t)b * S_ * H_ + h * HD_;

    // prologue: stage K(0); load V(0); hoist padding mask; load Q frags
    stage64_swz8((const char*)Kg, H_ * 2, Ksm, tid);
    int vr = tid & 63, vd0 = (tid >> 6) * 8;    // each thread owns (kv=vr, d=vd0..vd0+7)
    bf16x8 vreg = *reinterpret_cast<const bf16x8*>(Vg + (size_t)vr * H_ + vd0);
    {
        const int4* am4 = reinterpret_cast<const int4*>(amask + b * S_);
        int i = tid;
        if (i < S_ / 4) {
            int4 v = am4[i];
            uchar4 o;
            o.x = (v.x == 0); o.y = (v.y == 0); o.z = (v.z == 0); o.w = (v.w == 0);
            reinterpret_cast<uchar4*>(maskc)[i] = o;
        }
    }
    bf16x8 qf[4];
#pragma unroll
    for (int kk = 0; kk < 4; ++kk)
        qf[kk] = *reinterpret_cast<const bf16x8*>(Qg + kk * 16 + hi * 8);

    __syncthreads();  // prologue: K(0)/V(0) drained; maskc visible
    if (tid < 32) {   // per-64-kv "any masked" byte (covered by barrier #1 of t=0)
        const unsigned* mw = reinterpret_cast<const unsigned*>(maskc + tid * 64);
        unsigned o = 0;
#pragma unroll
        for (int i = 0; i < 16; ++i) o |= mw[i];
        anyz[tid] = o ? 1 : 0;
    }

    f32x16 oacc0, oacc1;
#pragma unroll
    for (int j = 0; j < 16; ++j) { oacc0[j] = 0.f; oacc1[j] = 0.f; }
    float mrun = -__builtin_inff(), lrun = 0.f;

    int T = 4 * qb + 4;
    for (int t = 0; t < T; ++t) {
        int kv0 = t * 64;
        const char* Kc = Ksm + (t & 1) * 8192;

        // scatter vreg (= V(t)) -> Vt, cheap factored swizzle addressing
        {
            unsigned short* vb = Vt + vd0 * 64 + (vr & 7);
            int rs3 = (vr >> 3) << 3;
#pragma unroll
            for (int j = 0; j < 8; ++j)
                vb[j * 64 + (rs3 ^ (j << 3))] = (unsigned short)vreg[j];
        }
        __syncthreads();  // #1: Vt visible; K(t) already drained (prev #2 / prologue)

        // stage K(t+1) into other buffer; prefetch V(t+1) into registers
        if (t + 1 < T)
            stage64_swz8((const char*)(Kg + (size_t)(kv0 + 64) * H_), H_ * 2,
                         Ksm + ((t + 1) & 1) * 8192, tid);
        {
            int kvn = (t + 1 < T) ? kv0 + 64 : kv0;
            vreg = *reinterpret_cast<const bf16x8*>(Vg + (size_t)(kvn + vr) * H_ + vd0);
        }

        int c0 = kv0, c1 = kv0 + 32;
        if (c0 <= Qwg) {             // wave-uniform: any visible work in this tile
            bool vis1 = (c1 <= Qwg);
            f32x16 sa0, sa1;
#pragma unroll
            for (int j = 0; j < 16; ++j) { sa0[j] = 0.f; sa1[j] = 0.f; }

            __builtin_amdgcn_s_setprio(1);
#pragma unroll
            for (int kk = 0; kk < 4; ++kk) {
                bf16x8 kf0 = frag_swz(Kc, l31, 2 * kk + hi);
                sa0 = __builtin_amdgcn_mfma_f32_32x32x16_bf16(kf0, qf[kk], sa0, 0, 0, 0);
                if (vis1) {
                    bf16x8 kf1 = frag_swz(Kc, 32 + l31, 2 * kk + hi);
                    sa1 = __builtin_amdgcn_mfma_f32_32x32x16_bf16(kf1, qf[kk], sa1, 0, 0, 0);
                }
            }
            __builtin_amdgcn_s_setprio(0);

            // causal: diagonal sub-block at most once per wave
            if (c0 == Qwg) {
#pragma unroll
                for (int r = 0; r < 16; ++r) sa0[r] = (cm & (1u << r)) ? -1e9f : sa0[r];
            }
            if (vis1 && c1 == Qwg) {
#pragma unroll
                for (int r = 0; r < 16; ++r) sa1[r] = (cm & (1u << r)) ? -1e9f : sa1[r];
            }
            // padding mask (skipped when this 64-kv group is all-ones)
            if (anyz[t]) {
#pragma unroll
                for (int u = 0; u < 4; ++u) {
                    uchar4 mk = *reinterpret_cast<const uchar4*>(maskc + kv0 + 8 * u + hi4);
                    if (mk.x) sa0[4 * u + 0] = -1e9f;
                    if (mk.y) sa0[4 * u + 1] = -1e9f;
                    if (mk.z) sa0[4 * u + 2] = -1e9f;
                    if (mk.w) sa0[4 * u + 3] = -1e9f;
                }
                if (vis1) {
#pragma unroll
                    for (int u = 0; u < 4; ++u) {
                        uchar4 mk = *reinterpret_cast<const uchar4*>(maskc + kv0 + 32 + 8 * u + hi4);
                        if (mk.x) sa1[4 * u + 0] = -1e9f;
                        if (mk.y) sa1[4 * u + 1] = -1e9f;
                        if (mk.z) sa1[4 * u + 2] = -1e9f;
                        if (mk.w) sa1[4 * u + 3] = -1e9f;
                    }
                }
            }

            // tree row-max; cross-half via shfl
            float mx = vmax16(sa0);
            if (vis1) mx = fmaxf(mx, vmax16(sa1));
            mx = fmaxf(mx, __shfl_xor(mx, 32));

            // threshold defer-rescale: only pay the O-pass when max grows by >10 (log2)
            if (__any(mx > mrun + 10.f)) {
                float mnew = fmaxf(mrun, mx);
                float fsc = exp2f_hw(mrun - mnew);
                mrun = mnew;
                lrun *= fsc;
#pragma unroll
                for (int j = 0; j < 16; ++j) { oacc0[j] *= fsc; oacc1[j] *= fsc; }
            }

            // fused per-n: exp2 -> pack bf16 -> permlane -> PV MFMA
            float rs = 0.f;
            __builtin_amdgcn_s_setprio(1);
#pragma unroll
            for (int n = 0; n < 2; ++n) {
                if (n == 1 && !vis1) break;
                const f32x16& sa = (n == 0) ? sa0 : sa1;
                unsigned int wrd[4][2];
#pragma unroll
                for (int u = 0; u < 4; ++u) {
                    float p0 = exp2f_hw(sa[4 * u + 0] - mrun);
                    float p1 = exp2f_hw(sa[4 * u + 1] - mrun);
                    float p2 = exp2f_hw(sa[4 * u + 2] - mrun);
                    float p3 = exp2f_hw(sa[4 * u + 3] - mrun);
                    rs += (p0 + p1) + (p2 + p3);
                    asm("v_cvt_pk_bf16_f32 %0, %1, %2" : "=v"(wrd[u][0]) : "v"(p0), "v"(p1));
                    asm("v_cvt_pk_bf16_f32 %0, %1, %2" : "=v"(wrd[u][1]) : "v"(p2), "v"(p3));
                }
#pragma unroll
                for (int half = 0; half < 2; ++half) {
                    int u0 = 2 * half;
                    unsigned int X0 = wrd[u0][0], Y0 = wrd[u0 + 1][0];
                    unsigned int X1 = wrd[u0][1], Y1 = wrd[u0 + 1][1];
                    asm("v_permlane32_swap_b32 %0, %1" : "+v"(X0), "+v"(Y0));
                    asm("v_permlane32_swap_b32 %0, %1" : "+v"(X1), "+v"(Y1));
                    union { unsigned int u[4]; bf16x8 v; } bu;
                    bu.u[0] = X0; bu.u[1] = X1; bu.u[2] = Y0; bu.u[3] = Y1;
                    int kc = 2 * n + half;
                    bf16x8 af0 = *reinterpret_cast<const bf16x8*>(
                        &Vt[(l31) * 64 + (((2 * kc + hi) ^ (l31 & 7)) << 3)]);
                    oacc0 = __builtin_amdgcn_mfma_f32_32x32x16_bf16(af0, bu.v, oacc0, 0, 0, 0);
                    bf16x8 af1 = *reinterpret_cast<const bf16x8*>(
                        &Vt[(32 + l31) * 64 + (((2 * kc + hi) ^ (l31 & 7)) << 3)]);
                    oacc1 = __builtin_amdgcn_mfma_f32_32x32x16_bf16(af1, bu.v, oacc1, 0, 0, 0);
                }
            }
            __builtin_amdgcn_s_setprio(0);

            rs += __shfl_xor(rs, 32);
            lrun += rs;
        }
        __syncthreads();  // #2: Vt reads done; K(t+1)/V(t+1) prefetch drained
    }

    // epilogue: divide by row sum, transpose O^T -> O via LDS (reuse all 32KB), store
    float inv = 1.f / lrun;
    unsigned short* Osm = reinterpret_cast<unsigned short*>(lds);
#pragma unroll
    for (int r = 0; r < 16; ++r) {
        int d = (r & 3) + 8 * (r >> 2) + hi4;
        Osm[w * 2048 + l31 * 64 + ((((d >> 3) ^ (l31 & 7)) << 3) | (d & 7))] = f2bf(oacc0[r] * inv);
        int d1 = d + 32;
        Osm[w * 2048 + l31 * 64 + ((((d1 >> 3) ^ (l31 & 7)) << 3) | (d1 & 7))] = f2bf(oacc1[r] * inv);
    }
    __syncthreads();
#pragma unroll
    for (int wv = 0; wv < 4; ++wv) {
        int q = tid >> 3, j = tid & 7;      // q 0..63
        int row = wv * 64 + q;              // 0..255
        bf16x8 vv = *reinterpret_cast<const bf16x8*>(
            Osm + (row >> 5) * 2048 + (row & 31) * 64 + ((j ^ (row & 7)) << 3));
        size_t grow = (size_t)(b * S_ + brow + row);
        *reinterpret_cast<bf16x8*>(Ab + grow * H_ + h * HD_ + j * 8) = vv;
    }
}

extern "C" void kernel_launch(void* const* d_in, const int* in_sizes, int n_in,
                              void* d_out, int out_size, void* d_ws, size_t ws_size,
                              hipStream_t stream) {
    const float* x  = (const float*)d_in[0];
    const int* amask = (const int*)d_in[1];
    const float* Wq = (const float*)d_in[2];
    const float* Wk = (const float*)d_in[3];
    const float* Wv = (const float*)d_in[4];
    const float* Wo = (const float*)d_in[5];
    const float* bo = (const float*)d_in[6];
    float* out = (float*)d_out;

    const size_t XN = (size_t)B_ * S_ * H_;   // 8388608
    const size_t WN = (size_t)H_ * H_;        // 1048576

    char* ws = (char*)d_ws;
    unsigned short* xb  = (unsigned short*)ws;           ws += XN * 2;
    unsigned short* Wqb = (unsigned short*)ws;           ws += WN * 2;
    unsigned short* Wkb = (unsigned short*)ws;           ws += WN * 2;
    unsigned short* Wvb = (unsigned short*)ws;           ws += WN * 2;
    unsigned short* Wob = (unsigned short*)ws;           ws += WN * 2;
    unsigned short* Qb  = (unsigned short*)ws;           ws += XN * 2;
    unsigned short* Kb  = (unsigned short*)ws;           ws += XN * 2;
    unsigned short* Vb  = (unsigned short*)ws;           ws += XN * 2;
    unsigned short* Ab  = (unsigned short*)ws;           ws += XN * 2;

    cast_all<<<12288, 256, 0, stream>>>(x, Wq, Wk, Wv, Wo, xb, Wqb, Wkb, Wvb, Wob);
    gemm_qkv<<<dim3(64, 24), 256, 0, stream>>>(xb, Wqb, Wkb, Wvb, Qb, Kb, Vb);
    attn<<<512, 512, 0, stream>>>(Qb, Kb, Vb, amask, Ab);
    gemm_out<<<dim3(64, 8), 256, 0, stream>>>(Ab, Wob, bo, out);
}